// Round 1
// baseline (279.497 us; speedup 1.0000x reference)
//
#include <hip/hip_runtime.h>
#include <hip/hip_bf16.h>

// ---------------------------------------------------------------------------
// CompressedGlobalAttention: B=2, S=8192, D=1024, H=16, Hd=64, R=8,
// local_window_start=4096 -> P=512 pools.
// Pipeline:
//   1. cast x -> bf16 (xb), transpose+cast weights -> Bt layout (N x K) bf16
//   2. compress: avg-pool x[:, :4096] -> cb (B*P x 1024) bf16
//   3. GEMM: Q = xb @ WqT^T + bq (bf16), K = cb@WkT^T+bk, V = cb@WvT^T+bv
//   4. attention per (b,h): scores=Q K^T * 0.125, causal pool mask, softmax,
//      out = P V  -> attn_out bf16 (reuses xb region)
//   5. GEMM: out = attn_out @ WoT^T + bo (f32 -> d_out)
// All matmuls use v_mfma_f32_16x16x32_bf16.
// Fragment layouts (gfx950, m89/m91-verified C/D; contiguous-8-K A/B):
//   A: lane holds A[row=l&15][k=(l>>4)*8 + i], i=0..7   (one b128)
//   B: lane holds B[k=(l>>4)*8 + i][col=l&15]           (one b128)
//   C/D: lane reg r -> row=(l>>4)*4+r, col=l&15
// ---------------------------------------------------------------------------

typedef __attribute__((ext_vector_type(8))) short bf16x8;
typedef __attribute__((ext_vector_type(4))) float f32x4;

#define MFMA_BF16(a, b, c) __builtin_amdgcn_mfma_f32_16x16x32_bf16((a), (b), (c), 0, 0, 0)

__device__ __forceinline__ unsigned short f2bu(float x) {
  __hip_bfloat16 b = __float2bfloat16(x);
  return __builtin_bit_cast(unsigned short, b);
}

__device__ __forceinline__ void gload_lds16(const void* g, void* l) {
  // async global->LDS, 16B per lane; LDS dest is wave-uniform base + lane*16
  __builtin_amdgcn_global_load_lds(
      (const __attribute__((address_space(1))) unsigned*)(g),
      (__attribute__((address_space(3))) unsigned*)(l), 16, 0, 0);
}

// ---------------------------------------------------------------------------
// cast x (f32) -> bf16, vectorized 4-wide
__global__ void cast_x_kernel(const float* __restrict__ x,
                              __hip_bfloat16* __restrict__ xb, int n4) {
  int i = blockIdx.x * blockDim.x + threadIdx.x;
  const int stride = gridDim.x * blockDim.x;
  for (; i < n4; i += stride) {
    float4 v = ((const float4*)x)[i];
    ushort4 o;
    o.x = f2bu(v.x); o.y = f2bu(v.y); o.z = f2bu(v.z); o.w = f2bu(v.w);
    ((ushort4*)xb)[i] = o;
  }
}

// ---------------------------------------------------------------------------
// transpose 1024x1024 f32 weight -> bf16 WT[n][k] = W[k][n]; blockIdx.z picks W
__global__ void transpose_w_kernel(const float* __restrict__ w0, const float* __restrict__ w1,
                                   const float* __restrict__ w2, const float* __restrict__ w3,
                                   __hip_bfloat16* __restrict__ t0, __hip_bfloat16* __restrict__ t1,
                                   __hip_bfloat16* __restrict__ t2, __hip_bfloat16* __restrict__ t3) {
  const float* W; __hip_bfloat16* T;
  switch (blockIdx.z) {
    case 0: W = w0; T = t0; break;
    case 1: W = w1; T = t1; break;
    case 2: W = w2; T = t2; break;
    default: W = w3; T = t3; break;
  }
  __shared__ float tile[32][33];
  const int tx = threadIdx.x, ty = threadIdx.y;     // 32 x 8
  const int k0 = blockIdx.x * 32, n0 = blockIdx.y * 32;
#pragma unroll
  for (int j = 0; j < 4; ++j) {
    const int kk = ty + j * 8;
    tile[kk][tx] = W[(size_t)(k0 + kk) * 1024 + n0 + tx];
  }
  __syncthreads();
#pragma unroll
  for (int j = 0; j < 4; ++j) {
    const int nn = ty + j * 8;
    T[(size_t)(n0 + nn) * 1024 + k0 + tx] = __float2bfloat16(tile[tx][nn]);
  }
}

// ---------------------------------------------------------------------------
// avg-pool compress: cb[b*512+p][d] = mean_{r<8} x[b][p*8+r][d]  (bf16 out)
__global__ void compress_kernel(const float* __restrict__ x,
                                __hip_bfloat16* __restrict__ cb) {
  const int bp = blockIdx.x;            // 0..1023
  const int b = bp >> 9, p = bp & 511;
  const int d = threadIdx.x * 4;
  float4 a = {0.f, 0.f, 0.f, 0.f};
#pragma unroll
  for (int r = 0; r < 8; ++r) {
    const float4 v = *(const float4*)&x[(size_t)(b * 8192 + p * 8 + r) * 1024 + d];
    a.x += v.x; a.y += v.y; a.z += v.z; a.w += v.w;
  }
  ushort4 o;
  o.x = f2bu(a.x * 0.125f); o.y = f2bu(a.y * 0.125f);
  o.z = f2bu(a.z * 0.125f); o.w = f2bu(a.w * 0.125f);
  *(ushort4*)&cb[(size_t)bp * 1024 + d] = o;
}

// ---------------------------------------------------------------------------
// C(MxN) = A(MxK) @ Bt(NxK)^T + bias ; m97-style 128x128x32 tile, 4 waves 2x2
template <typename OUT_T>
__global__ __launch_bounds__(256, 2) void gemm_bt_kernel(
    const __hip_bfloat16* __restrict__ A, const __hip_bfloat16* __restrict__ Bt,
    const float* __restrict__ bias, OUT_T* __restrict__ C, int M, int N, int K) {
  __shared__ alignas(16) __hip_bfloat16 As[128 * 32];
  __shared__ alignas(16) __hip_bfloat16 Bs[128 * 32];
  const int tid = threadIdx.x;
  const int wave = tid >> 6, lane = tid & 63;
  const int l15 = lane & 15, lg = lane >> 4;
  const long brow = (long)blockIdx.y * 128;
  const long bcol = (long)blockIdx.x * 128;
  const int wr = (wave >> 1) * 64;    // wave row offset in tile
  const int wc = (wave & 1) * 64;     // wave col offset in tile

  f32x4 zero = {0.f, 0.f, 0.f, 0.f};
  f32x4 acc[4][4];
#pragma unroll
  for (int m = 0; m < 4; ++m)
#pragma unroll
    for (int n = 0; n < 4; ++n) acc[m][n] = zero;

  for (int kt = 0; kt < K; kt += 32) {
    // stage A,B tiles: 8KB each; 8 wave-segments x 1024B
#pragma unroll
    for (int j = 0; j < 2; ++j) {
      const int seg = wave * 2 + j;         // 0..7
      const int o = seg * 1024;             // uniform LDS byte base
      const int ob = o + lane * 16;         // per-lane linear byte in tile
      const int row = ob >> 6;              // 64B (32 bf16) per row
      const int cb = ob & 63;
      gload_lds16((const char*)A + ((brow + row) * (long)K + kt) * 2 + cb, (char*)As + o);
      gload_lds16((const char*)Bt + ((bcol + row) * (long)K + kt) * 2 + cb, (char*)Bs + o);
    }
    __syncthreads();   // drains vmcnt (global_load_lds) + syncs
    bf16x8 af[4], bfr[4];
#pragma unroll
    for (int m = 0; m < 4; ++m)
      af[m] = *(const bf16x8*)&As[(wr + m * 16 + l15) * 32 + lg * 8];
#pragma unroll
    for (int n = 0; n < 4; ++n)
      bfr[n] = *(const bf16x8*)&Bs[(wc + n * 16 + l15) * 32 + lg * 8];
#pragma unroll
    for (int m = 0; m < 4; ++m)
#pragma unroll
      for (int n = 0; n < 4; ++n)
        acc[m][n] = MFMA_BF16(af[m], bfr[n], acc[m][n]);
    __syncthreads();   // all reads done before next stage overwrites
  }

#pragma unroll
  for (int m = 0; m < 4; ++m)
#pragma unroll
    for (int n = 0; n < 4; ++n) {
      const long col = bcol + wc + n * 16 + l15;
      const float bv = bias[col];
#pragma unroll
      for (int r = 0; r < 4; ++r) {
        const long row = brow + wr + m * 16 + lg * 4 + r;
        const float v = acc[m][n][r] + bv;
        if constexpr (sizeof(OUT_T) == 2)
          C[row * N + col] = __float2bfloat16(v);
        else
          C[row * N + col] = v;
      }
    }
}

// ---------------------------------------------------------------------------
// attention: per (b,h) block-column of queries.
// grid (32, 16), block 512 (8 waves). Each wave: 4 iterations of 16 q-rows.
__global__ __launch_bounds__(512, 2) void attn_kernel(
    const __hip_bfloat16* __restrict__ Q,   // (B*S) x 1024
    const __hip_bfloat16* __restrict__ Km,  // (B*P) x 1024
    const __hip_bfloat16* __restrict__ Vm,  // (B*P) x 1024
    __hip_bfloat16* __restrict__ O) {       // (B*S) x 1024
  __shared__ alignas(16) __hip_bfloat16 Ks[512 * 64];   // [p][d], rows XOR-swizzled
  __shared__ alignas(16) __hip_bfloat16 VT[64 * 512];   // [d][p], rows XOR-swizzled
  __shared__ alignas(16) __hip_bfloat16 Pb[8][16 * 32]; // per-wave P relayout buffer
  const int bh = blockIdx.x;
  const int b = bh >> 4, h = bh & 15;
  const int tid = threadIdx.x, wave = tid >> 6, lane = tid & 63;
  const int l15 = lane & 15, lg = lane >> 4;
  const __hip_bfloat16* Kbase = Km + (size_t)b * 512 * 1024 + h * 64;
  const __hip_bfloat16* Vbase = Vm + (size_t)b * 512 * 1024 + h * 64;

  // ---- stage K: linear LDS dest, XOR-swizzled global source (m173 pattern)
  // read side will use byte_in_row ^ ((p&7)<<4), so source pre-applies it.
#pragma unroll
  for (int j = 0; j < 8; ++j) {
    const int seg = wave * 8 + j;           // 64 segments x 8 rows
    const int p = seg * 8 + (lane >> 3);
    const int cb = ((lane & 7) * 16) ^ ((p & 7) << 4);
    gload_lds16((const char*)Kbase + (size_t)p * 2048 + cb, (char*)Ks + seg * 1024);
  }
  // ---- stage V transposed (VT[d][p]) + swizzled, register staging
#pragma unroll
  for (int it = 0; it < 8; ++it) {
    const int c = tid + it * 512;           // 0..4095 chunks of 8 elems
    const int p = c >> 3;
    const int d0 = (c & 7) * 8;
    uint4 vv = *(const uint4*)((const char*)Vbase + (size_t)p * 2048 + d0 * 2);
    const unsigned short* e = (const unsigned short*)&vv;
#pragma unroll
    for (int ei = 0; ei < 8; ++ei) {
      const int d = d0 + ei;
      const int byte = d * 1024 + ((p * 2) ^ ((d & 7) << 4));
      *(unsigned short*)((char*)VT + byte) = e[ei];
    }
  }
  __syncthreads();

  const int qb0 = blockIdx.y * 512;
  for (int itq = 0; itq < 4; ++itq) {
    const int q0 = qb0 + itq * 128 + wave * 16;   // local q (0..8191)
    const __hip_bfloat16* Qrow = Q + (size_t)(b * 8192 + q0 + l15) * 1024 + h * 64;
    const bf16x8 qf0 = *(const bf16x8*)(Qrow + lg * 8);        // d 0..31
    const bf16x8 qf1 = *(const bf16x8*)(Qrow + 32 + lg * 8);   // d 32..63

    // ---- scores: lane holds s[c][r] = scores[q0+lg*4+r][c*16+l15]
    f32x4 s[32];
#pragma unroll
    for (int c = 0; c < 32; ++c) {
      const int p = c * 16 + l15;
      const int rb = p * 128;
      const int c0 = (lg * 16) ^ ((p & 7) << 4);
      const int c1 = (lg * 16 + 64) ^ ((p & 7) << 4);
      const bf16x8 kf0 = *(const bf16x8*)((const char*)Ks + rb + c0);
      const bf16x8 kf1 = *(const bf16x8*)((const char*)Ks + rb + c1);
      f32x4 z = {0.f, 0.f, 0.f, 0.f};
      z = MFMA_BF16(qf0, kf0, z);
      z = MFMA_BF16(qf1, kf1, z);
      s[c] = z;
    }
    // ---- mask + scale + row max
    float mrow[4];
#pragma unroll
    for (int r = 0; r < 4; ++r) mrow[r] = -3e38f;
#pragma unroll
    for (int c = 0; c < 32; ++c) {
      const int p = c * 16 + l15;
#pragma unroll
      for (int r = 0; r < 4; ++r) {
        const int qa = q0 + lg * 4 + r;
        const bool valid = qa >= (p + 1) * 8;
        // rows with q<8 have no valid pool -> reference softmax is uniform:
        // use score 0 everywhere for those rows.
        const float v = valid ? s[c][r] * 0.125f : (qa >= 8 ? -3e38f : 0.f);
        s[c][r] = v;
        mrow[r] = fmaxf(mrow[r], v);
      }
    }
#pragma unroll
    for (int r = 0; r < 4; ++r) {
      mrow[r] = fmaxf(mrow[r], __shfl_xor(mrow[r], 1));
      mrow[r] = fmaxf(mrow[r], __shfl_xor(mrow[r], 2));
      mrow[r] = fmaxf(mrow[r], __shfl_xor(mrow[r], 4));
      mrow[r] = fmaxf(mrow[r], __shfl_xor(mrow[r], 8));
    }
    // ---- exp + row sum
    float lsum[4] = {0.f, 0.f, 0.f, 0.f};
#pragma unroll
    for (int c = 0; c < 32; ++c)
#pragma unroll
      for (int r = 0; r < 4; ++r) {
        const float e = exp2f((s[c][r] - mrow[r]) * 1.44269504f);
        s[c][r] = e;
        lsum[r] += e;
      }
#pragma unroll
    for (int r = 0; r < 4; ++r) {
      lsum[r] += __shfl_xor(lsum[r], 1);
      lsum[r] += __shfl_xor(lsum[r], 2);
      lsum[r] += __shfl_xor(lsum[r], 4);
      lsum[r] += __shfl_xor(lsum[r], 8);
      lsum[r] = 1.f / lsum[r];
    }
    // ---- PV: bounce normalized P through per-wave LDS to A-operand layout
    f32x4 o4[4];
#pragma unroll
    for (int d = 0; d < 4; ++d) o4[d] = (f32x4){0.f, 0.f, 0.f, 0.f};
    __hip_bfloat16* Pw = &Pb[wave][0];    // [16 q][32 p] per k-chunk
#pragma unroll
    for (int kc = 0; kc < 16; ++kc) {
#pragma unroll
      for (int cc = 0; cc < 2; ++cc) {
        const int c = kc * 2 + cc;
#pragma unroll
        for (int r = 0; r < 4; ++r)
          Pw[(lg * 4 + r) * 32 + cc * 16 + l15] =
              __float2bfloat16(s[c][r] * lsum[r]);
      }
      // A-frag: P[q=l15][p=lg*8+i]  (same-wave LDS RAW: DS pipe is in-order)
      const bf16x8 af = *(const bf16x8*)&Pw[l15 * 32 + lg * 8];
#pragma unroll
      for (int db = 0; db < 4; ++db) {
        const int d = db * 16 + l15;
        const int byte = d * 1024 + ((kc * 64 + lg * 16) ^ ((d & 7) << 4));
        const bf16x8 vf = *(const bf16x8*)((const char*)VT + byte);
        o4[db] = MFMA_BF16(af, vf, o4[db]);
      }
    }
    // ---- write attn_out
    __hip_bfloat16* Op = O + (size_t)(b * 8192 + q0) * 1024 + h * 64;
#pragma unroll
    for (int db = 0; db < 4; ++db)
#pragma unroll
      for (int r = 0; r < 4; ++r)
        Op[(size_t)(lg * 4 + r) * 1024 + db * 16 + l15] =
            __float2bfloat16(o4[db][r]);
  }
}

// ---------------------------------------------------------------------------
extern "C" void kernel_launch(void* const* d_in, const int* in_sizes, int n_in,
                              void* d_out, int out_size, void* d_ws, size_t ws_size,
                              hipStream_t stream) {
  const float* x  = (const float*)d_in[0];
  // d_in[1] = local_window_start (structure hardcoded for 4096)
  const float* Wq = (const float*)d_in[2];
  const float* bq = (const float*)d_in[3];
  const float* Wk = (const float*)d_in[4];
  const float* bk = (const float*)d_in[5];
  const float* Wv = (const float*)d_in[6];
  const float* bv = (const float*)d_in[7];
  const float* Wo = (const float*)d_in[8];
  const float* bo = (const float*)d_in[9];
  float* out = (float*)d_out;

  constexpr size_t SZ_XB = (size_t)16384 * 1024 * 2;  // 32 MB
  constexpr size_t SZ_WT = (size_t)1024 * 1024 * 2;   // 2 MB
  constexpr size_t SZ_CB = (size_t)1024 * 1024 * 2;   // 2 MB (B*P rows)
  char* ws = (char*)d_ws;
  __hip_bfloat16* xb   = (__hip_bfloat16*)ws;                                   // also attn_out
  __hip_bfloat16* WqT  = (__hip_bfloat16*)(ws + SZ_XB);
  __hip_bfloat16* WkT  = (__hip_bfloat16*)(ws + SZ_XB + SZ_WT);
  __hip_bfloat16* WvT  = (__hip_bfloat16*)(ws + SZ_XB + 2 * SZ_WT);
  __hip_bfloat16* WoT  = (__hip_bfloat16*)(ws + SZ_XB + 3 * SZ_WT);
  __hip_bfloat16* cbuf = (__hip_bfloat16*)(ws + SZ_XB + 4 * SZ_WT);
  __hip_bfloat16* Qb   = (__hip_bfloat16*)(ws + SZ_XB + 4 * SZ_WT + SZ_CB);
  __hip_bfloat16* Kb   = (__hip_bfloat16*)(ws + SZ_XB + 4 * SZ_WT + SZ_CB + SZ_XB);
  __hip_bfloat16* Vb   = (__hip_bfloat16*)(ws + SZ_XB + 4 * SZ_WT + SZ_CB + SZ_XB + SZ_CB);

  // 1. casts / transpose / compress
  cast_x_kernel<<<dim3(2048), dim3(256), 0, stream>>>(x, xb, 4194304);
  transpose_w_kernel<<<dim3(32, 32, 4), dim3(32, 8), 0, stream>>>(
      Wq, Wk, Wv, Wo, WqT, WkT, WvT, WoT);
  compress_kernel<<<dim3(1024), dim3(256), 0, stream>>>(x, cbuf);
  // 2. projections
  gemm_bt_kernel<__hip_bfloat16><<<dim3(8, 128), dim3(256), 0, stream>>>(
      xb, WqT, bq, Qb, 16384, 1024, 1024);
  gemm_bt_kernel<__hip_bfloat16><<<dim3(8, 8), dim3(256), 0, stream>>>(
      cbuf, WkT, bk, Kb, 1024, 1024, 1024);
  gemm_bt_kernel<__hip_bfloat16><<<dim3(8, 8), dim3(256), 0, stream>>>(
      cbuf, WvT, bv, Vb, 1024, 1024, 1024);
  // 3. attention (writes attn_out into xb region; xb dead after Q GEMM)
  attn_kernel<<<dim3(32, 16), dim3(512), 0, stream>>>(Qb, Kb, Vb, xb);
  // 4. output projection -> f32 d_out
  gemm_bt_kernel<float><<<dim3(8, 128), dim3(256), 0, stream>>>(
      xb, WoT, bo, out, 16384, 1024, 1024);
}